// Round 2
// baseline (817.554 us; speedup 1.0000x reference)
//
#include <hip/hip_runtime.h>
#include <hip/hip_fp16.h>
#include <hip/hip_cooperative_groups.h>

namespace cg = cooperative_groups;

// Graph scaled-dot-product attention, N=50000, E=800000, H=8, D=64.
// seg_sum[n] = Q[n] @ (sum_{e:A_e=n} K[B_e])^T -- only Ksum needed per node.
// k pre-converted to f16 to halve gather bytes.
//
// THIS ROUND: single cooperative mega-kernel (1 dispatch instead of 5-8).
// Theory: harness shows ~35-45us per-dispatch overhead; round-1's 1-block
// scanmat was ~130us of serial single-CU work. Fix both: grid.sync() phases,
// all scan work multi-block. Node math identical to round 1 (passed, 0.0156).

#define ROW 512          // H*D floats per node
#define LPAD 68          // padded LDS row stride (floats)
#define EPB 2048         // edges per hist/scatter chunk (256 thr * 8)

typedef float f4 __attribute__((ext_vector_type(4)));
typedef unsigned int u4 __attribute__((ext_vector_type(4)));

// ================= device phase functions =================

__device__ __forceinline__ void dev_convert(const float* __restrict__ k,
                                            unsigned int* __restrict__ kh, int i) {
    const f4* src = (const f4*)k + (size_t)i * 2;
    f4 x0 = __builtin_nontemporal_load(src);       // k f32 read once
    f4 x1 = __builtin_nontemporal_load(src + 1);
    union { __half2 h2; unsigned int u; } c0, c1, c2, c3;
    c0.h2 = __floats2half2_rn(x0.x, x0.y);
    c1.h2 = __floats2half2_rn(x0.z, x0.w);
    c2.h2 = __floats2half2_rn(x1.x, x1.y);
    c3.h2 = __floats2half2_rn(x1.z, x1.w);
    u4 o = {c0.u, c1.u, c2.u, c3.u};
    ((u4*)kh)[i] = o;
}

__device__ __forceinline__ void dev_hist(const int* __restrict__ A, int* __restrict__ bh,
                                         int E, int HB, int NB, int blk, int t, int* h) {
    __syncthreads();                 // protect h reuse across loop iters / phases
    h[t] = 0;
    __syncthreads();
    int base = blk * EPB + t * 8;
    if (base + 8 <= E) {
        int4 a0 = *(const int4*)(A + base);
        int4 a1 = *(const int4*)(A + base + 4);
        atomicAdd(&h[a0.x >> 8], 1); atomicAdd(&h[a0.y >> 8], 1);
        atomicAdd(&h[a0.z >> 8], 1); atomicAdd(&h[a0.w >> 8], 1);
        atomicAdd(&h[a1.x >> 8], 1); atomicAdd(&h[a1.y >> 8], 1);
        atomicAdd(&h[a1.z >> 8], 1); atomicAdd(&h[a1.w >> 8], 1);
    } else {
        for (int j = 0; j < 8; ++j) { int i = base + j; if (i < E) atomicAdd(&h[A[i] >> 8], 1); }
    }
    __syncthreads();
    if (t < NB) bh[t * HB + blk] = h[t];   // bucket-major matrix
}

// block-wide exclusive scan over 256 ints (needs scr[4]+)
__device__ __forceinline__ int excl_scan_256(int x, int t, int* scr) {
    int lane = t & 63, w = t >> 6;
    int v = x;
    #pragma unroll
    for (int off = 1; off < 64; off <<= 1) {
        int u = __shfl_up(v, off, 64);
        if (lane >= off) v += u;
    }
    __syncthreads();                 // protect scr from previous use
    if (lane == 63) scr[w] = v;
    __syncthreads();
    int base = 0;
    #pragma unroll
    for (int i = 0; i < 4; ++i) if (i < w) base += scr[i];
    return base + v - x;             // exclusive prefix
}

__device__ __forceinline__ void dev_rowsum(const int* __restrict__ bh, int* __restrict__ rowsum,
                                           int HB, int g, int t, int* scr) {
    int s = 0;
    for (int c = t; c < HB; c += 256) s += bh[g * HB + c];
    #pragma unroll
    for (int off = 32; off; off >>= 1) s += __shfl_down(s, off, 64);
    int lane = t & 63, w = t >> 6;
    __syncthreads();                 // protect scr reuse
    if (lane == 0) scr[w] = s;
    __syncthreads();
    if (t == 0) rowsum[g] = scr[0] + scr[1] + scr[2] + scr[3];
}

__device__ __forceinline__ void dev_scanbase(const int* __restrict__ rowsum, int* __restrict__ rowbase,
                                             int* __restrict__ offsets, int NB, int N, int E,
                                             int t, int* scr) {
    int x = (t < NB) ? rowsum[t] : 0;
    int p = excl_scan_256(x, t, scr);
    if (t <= NB) rowbase[t] = p;     // rowbase[NB] == E
    if (t == 0) offsets[N] = E;
}

__device__ __forceinline__ void dev_rowscan(int* __restrict__ bh, const int* __restrict__ rowbase,
                                            int HB, int g, int t, int* scr) {
    int j0 = 2 * t, j1 = 2 * t + 1;
    int c0 = (j0 < HB) ? bh[g * HB + j0] : 0;
    int c1 = (j1 < HB) ? bh[g * HB + j1] : 0;
    int p = excl_scan_256(c0 + c1, t, scr);
    int base = rowbase[g];
    if (j0 < HB) bh[g * HB + j0] = base + p;
    if (j1 < HB) bh[g * HB + j1] = base + p + c0;
}

__device__ __forceinline__ void dev_scatter(const int* __restrict__ A, const int* __restrict__ Bs,
                                            const int* __restrict__ bh, int* __restrict__ tmp,
                                            int E, int HB, int NB, int blk, int t, int* cur) {
    __syncthreads();                 // protect cur reuse
    if (t < NB) cur[t] = bh[t * HB + blk];
    __syncthreads();
    int base = blk * EPB + t * 8;
    bool bal = ((((unsigned long long)(size_t)Bs) & 15) == 0);
    if (base + 8 <= E && bal) {
        int4 a0 = *(const int4*)(A + base);
        int4 a1 = *(const int4*)(A + base + 4);
        int4 b0 = *(const int4*)(Bs + base);
        int4 b1 = *(const int4*)(Bs + base + 4);
        int as[8] = {a0.x, a0.y, a0.z, a0.w, a1.x, a1.y, a1.z, a1.w};
        int bs[8] = {b0.x, b0.y, b0.z, b0.w, b1.x, b1.y, b1.z, b1.w};
        #pragma unroll
        for (int j = 0; j < 8; ++j) {
            int pos = atomicAdd(&cur[as[j] >> 8], 1);      // LDS atomic
            tmp[pos] = ((as[j] & 255) << 24) | bs[j];      // pack (A&255, B)
        }
    } else {
        for (int j = 0; j < 8; ++j) {
            int i = base + j;
            if (i < E) {
                int a = A[i], b = Bs[i];
                int pos = atomicAdd(&cur[a >> 8], 1);
                tmp[pos] = ((a & 255) << 24) | b;
            }
        }
    }
}

__device__ __forceinline__ void dev_build(const int* __restrict__ rowbase, const int* __restrict__ tmp,
                                          int* __restrict__ offsets, int* __restrict__ srcs,
                                          int N, int E, int NB, int g, int t, int* cnt, int* scr) {
    int s = rowbase[g];
    int e = rowbase[g + 1];
    __syncthreads();                 // protect cnt reuse
    cnt[t] = 0;
    __syncthreads();
    for (int i = s + t; i < e; i += 256) atomicAdd(&cnt[(tmp[i] >> 24) & 255], 1);
    __syncthreads();
    int val = cnt[t];
    int p = excl_scan_256(val, t, scr);
    int n0 = (g << 8) + t;
    if (n0 < N) offsets[n0] = s + p;
    __syncthreads();
    cnt[t] = s + p;                  // reuse as cursor
    __syncthreads();
    for (int i = s + t; i < e; i += 256) {
        int wv = tmp[i];
        int pos = atomicAdd(&cnt[(wv >> 24) & 255], 1);   // LDS atomic
        srcs[pos] = wv & 0xFFFFFF;
    }
}

// ---------------- f16 accumulate helper ----------------
__device__ __forceinline__ void acc8(u4 x, f4& a0, f4& a1) {
    union { unsigned int u; __half2 h; } p0{x.x}, p1{x.y}, p2{x.z}, p3{x.w};
    a0.x += __low2float(p0.h); a0.y += __high2float(p0.h);
    a0.z += __low2float(p1.h); a0.w += __high2float(p1.h);
    a1.x += __low2float(p2.h); a1.y += __high2float(p2.h);
    a1.z += __low2float(p3.h); a1.w += __high2float(p3.h);
}

// ---------------- per-node pipeline, f16 k (one wave per node) ----------------
__device__ __forceinline__ void dev_node16(const float* __restrict__ q,
                                           const unsigned int* __restrict__ kh,
                                           const float* __restrict__ v,
                                           const int* __restrict__ offsets,
                                           const int* __restrict__ srcs,
                                           float* __restrict__ out, int N, int n,
                                           int lane, float* qs, float* ks, float* ps) {
    bool active = n < N;
    int start = 0, end = 0;
    if (active) {
        start = __builtin_amdgcn_readfirstlane(offsets[n]);
        end   = __builtin_amdgcn_readfirstlane(offsets[n + 1]);
        int r0 = lane >> 4;
        int dq = (lane & 15) * 4;
        const f4* qn = (const f4*)(q + (size_t)n * ROW);
        f4 q0 = __builtin_nontemporal_load(qn + lane);
        f4 q1 = __builtin_nontemporal_load(qn + 64 + lane);
        *(f4*)(qs + r0 * LPAD + dq)       = q0;
        *(f4*)(qs + (r0 + 4) * LPAD + dq) = q1;
    }

    const u4* kh4 = (const u4*)kh;   // one u4 = 8 halves; one row = 64 u4
    f4 a0 = {0.f, 0.f, 0.f, 0.f}, a1 = {0.f, 0.f, 0.f, 0.f};
    int e = start;
    for (; e + 8 <= end; e += 8) {   // 8 independent 16B loads in flight
        int b0 = srcs[e],     b1 = srcs[e + 1], b2 = srcs[e + 2], b3 = srcs[e + 3];
        int b4 = srcs[e + 4], b5 = srcs[e + 5], b6 = srcs[e + 6], b7 = srcs[e + 7];
        u4 x0 = kh4[(size_t)b0 * 64 + lane];
        u4 x1 = kh4[(size_t)b1 * 64 + lane];
        u4 x2 = kh4[(size_t)b2 * 64 + lane];
        u4 x3 = kh4[(size_t)b3 * 64 + lane];
        u4 x4 = kh4[(size_t)b4 * 64 + lane];
        u4 x5 = kh4[(size_t)b5 * 64 + lane];
        u4 x6 = kh4[(size_t)b6 * 64 + lane];
        u4 x7 = kh4[(size_t)b7 * 64 + lane];
        acc8(x0, a0, a1); acc8(x1, a0, a1); acc8(x2, a0, a1); acc8(x3, a0, a1);
        acc8(x4, a0, a1); acc8(x5, a0, a1); acc8(x6, a0, a1); acc8(x7, a0, a1);
    }
    for (; e + 4 <= end; e += 4) {
        int b0 = srcs[e], b1 = srcs[e + 1], b2 = srcs[e + 2], b3 = srcs[e + 3];
        u4 x0 = kh4[(size_t)b0 * 64 + lane];
        u4 x1 = kh4[(size_t)b1 * 64 + lane];
        u4 x2 = kh4[(size_t)b2 * 64 + lane];
        u4 x3 = kh4[(size_t)b3 * 64 + lane];
        acc8(x0, a0, a1); acc8(x1, a0, a1); acc8(x2, a0, a1); acc8(x3, a0, a1);
    }
    for (; e < end; ++e) {
        u4 x = kh4[(size_t)srcs[e] * 64 + lane];
        acc8(x, a0, a1);
    }

    if (active) {
        // lane holds Ksum flat elems [lane*8, lane*8+8): row g = lane>>3, d=(lane&7)*8+j
        int g = lane >> 3;
        int dbase = (lane & 7) * 8;
        *(f4*)(ks + g * LPAD + dbase)     = a0;
        *(f4*)(ks + g * LPAD + dbase + 4) = a1;
    }
    __syncthreads();

    if (active) {
        int h = lane >> 3, g = lane & 7;
        const f4* qrow = (const f4*)(qs + h * LPAD);
        const f4* krow = (const f4*)(ks + g * LPAD);
        float acc = 0.f;
        #pragma unroll
        for (int i = 0; i < 16; ++i) {
            f4 qa = qrow[i];
            f4 kb = krow[i];
            acc += qa.x * kb.x + qa.y * kb.y + qa.z * kb.z + qa.w * kb.w;
        }
        int cnt = end - start;
        float score = acc / (float)((cnt > 0) ? cnt : 1);
        float mx = score;
        #pragma unroll
        for (int off = 1; off < 8; off <<= 1)
            mx = fmaxf(mx, __shfl_xor(mx, off, 8));
        float ex = __expf(score - mx);
        float sm = ex;
        #pragma unroll
        for (int off = 1; off < 8; off <<= 1)
            sm += __shfl_xor(sm, off, 8);
        ps[h * 8 + g] = ex / sm;
    }
    __syncthreads();

    if (active) {
        int h0 = lane >> 4;
        int dbase = (lane & 15) * 4;
        const float* vb = v + (size_t)n * ROW;
        f4 o0 = {0.f, 0.f, 0.f, 0.f}, o1 = {0.f, 0.f, 0.f, 0.f};
        #pragma unroll
        for (int g = 0; g < 8; ++g) {
            f4 vg = __builtin_nontemporal_load((const f4*)(vb + g * 64 + dbase));
            float p0 = ps[h0 * 8 + g];
            float p1 = ps[(h0 + 4) * 8 + g];
            o0 += p0 * vg;
            o1 += p1 * vg;
        }
        f4* ob = (f4*)(out + (size_t)n * ROW);
        __builtin_nontemporal_store(o0, ob + lane);
        __builtin_nontemporal_store(o1, ob + 64 + lane);
    }
}

// ---------------- per-node pipeline, f32 k (fallback) ----------------
__device__ __forceinline__ void dev_node32(const float* __restrict__ q, const float* __restrict__ k,
                                           const float* __restrict__ v,
                                           const int* __restrict__ offsets,
                                           const int* __restrict__ srcs,
                                           float* __restrict__ out, int N, int n,
                                           int lane, float* qs, float* ks, float* ps) {
    bool active = n < N;
    int start = 0, end = 0;
    if (active) { start = offsets[n]; end = offsets[n + 1]; }

    f4 a0 = {0.f, 0.f, 0.f, 0.f}, a1 = {0.f, 0.f, 0.f, 0.f};
    for (int e = start; e < end; ++e) {
        int b = srcs[e];
        const f4* kb = (const f4*)(k + (size_t)b * ROW);
        f4 x0 = kb[lane];
        f4 x1 = kb[64 + lane];
        a0 += x0; a1 += x1;
    }

    if (active) {
        int r0 = lane >> 4;
        int dbase = (lane & 15) * 4;
        *(f4*)(ks + r0 * LPAD + dbase)       = a0;
        *(f4*)(ks + (r0 + 4) * LPAD + dbase) = a1;
        const f4* qn = (const f4*)(q + (size_t)n * ROW);
        f4 q0 = qn[lane], q1 = qn[64 + lane];
        *(f4*)(qs + r0 * LPAD + dbase)       = q0;
        *(f4*)(qs + (r0 + 4) * LPAD + dbase) = q1;
    }
    __syncthreads();

    if (active) {
        int h = lane >> 3, g = lane & 7;
        const f4* qrow = (const f4*)(qs + h * LPAD);
        const f4* krow = (const f4*)(ks + g * LPAD);
        float acc = 0.f;
        #pragma unroll
        for (int i = 0; i < 16; ++i) {
            f4 qa = qrow[i];
            f4 kb = krow[i];
            acc += qa.x * kb.x + qa.y * kb.y + qa.z * kb.z + qa.w * kb.w;
        }
        int cnt = end - start;
        float score = acc / (float)((cnt > 0) ? cnt : 1);
        float mx = score;
        #pragma unroll
        for (int off = 1; off < 8; off <<= 1)
            mx = fmaxf(mx, __shfl_xor(mx, off, 8));
        float ex = __expf(score - mx);
        float sm = ex;
        #pragma unroll
        for (int off = 1; off < 8; off <<= 1)
            sm += __shfl_xor(sm, off, 8);
        ps[h * 8 + g] = ex / sm;
    }
    __syncthreads();

    if (active) {
        int h0 = lane >> 4;
        int dbase = (lane & 15) * 4;
        const float* vb = v + (size_t)n * ROW;
        f4 o0 = {0.f, 0.f, 0.f, 0.f}, o1 = {0.f, 0.f, 0.f, 0.f};
        #pragma unroll
        for (int g = 0; g < 8; ++g) {
            f4 vg = *(const f4*)(vb + g * 64 + dbase);
            float p0 = ps[h0 * 8 + g];
            float p1 = ps[(h0 + 4) * 8 + g];
            o0 += p0 * vg;
            o1 += p1 * vg;
        }
        f4* ob = (f4*)(out + (size_t)n * ROW);
        ob[lane]      = o0;
        ob[64 + lane] = o1;
    }
}

// ================= cooperative mega-kernel =================
__global__ __launch_bounds__(256, 4) void mega_kernel(
    const float* __restrict__ q, const float* __restrict__ k, const float* __restrict__ v,
    const int* __restrict__ A, const int* __restrict__ Bs,
    unsigned int* __restrict__ kh, int* __restrict__ offsets, int* __restrict__ srcs,
    int* __restrict__ tmp, int* __restrict__ bh, int* __restrict__ rowsum,
    int* __restrict__ rowbase, float* __restrict__ out,
    int N, int E, int HB, int NB, int total8, int usef16)
{
    __shared__ float lds[4][1160];   // node phase layout; aliased by earlier phases
    int* ib = (int*)&lds[0][0];      // ib[0..255] counters, ib[256..263] scan scratch
    int t = threadIdx.x;
    int G = gridDim.x;
    cg::grid_group grid = cg::this_grid();

    // ---- phase A: convert k->f16 (all blocks) + histogram (first HB block slots)
    if (usef16) {
        for (int i = blockIdx.x * 256 + t; i < total8; i += G * 256) dev_convert(k, kh, i);
    }
    for (int blk = blockIdx.x; blk < HB; blk += G) dev_hist(A, bh, E, HB, NB, blk, t, ib);
    grid.sync();

    // ---- phase B1: per-bucket row sums
    for (int g = blockIdx.x; g < NB; g += G) dev_rowsum(bh, rowsum, HB, g, t, ib + 256);
    grid.sync();

    // ---- phase B2: scan bucket bases (one block, 256-wide, trivial size)
    if (blockIdx.x == 0) dev_scanbase(rowsum, rowbase, offsets, NB, N, E, t, ib + 256);
    grid.sync();

    // ---- phase B3: exclusive scan along each bucket row (parallel per bucket)
    for (int g = blockIdx.x; g < NB; g += G) dev_rowscan(bh, rowbase, HB, g, t, ib + 256);
    grid.sync();

    // ---- phase C: scatter edges into bucket order
    for (int blk = blockIdx.x; blk < HB; blk += G) dev_scatter(A, Bs, bh, tmp, E, HB, NB, blk, t, ib);
    grid.sync();

    // ---- phase D: per-bucket offsets + srcs
    for (int g = blockIdx.x; g < NB; g += G) dev_build(rowbase, tmp, offsets, srcs, N, E, NB, g, t, ib, ib + 256);
    grid.sync();

    // ---- phase E: node attention, grid-strided (4 nodes / block / iter)
    int lane = t & 63, wid = t >> 6;
    int ngrp = (N + 3) >> 2;
    float* qs = &lds[wid][0];
    float* ks = qs + 8 * LPAD;
    float* ps = ks + 8 * LPAD;
    if (usef16) {
        for (int grp = blockIdx.x; grp < ngrp; grp += G)
            dev_node16(q, kh, v, offsets, srcs, out, N, grp * 4 + wid, lane, qs, ks, ps);
    } else {
        for (int grp = blockIdx.x; grp < ngrp; grp += G)
            dev_node32(q, k, v, offsets, srcs, out, N, grp * 4 + wid, lane, qs, ks, ps);
    }
}

// ================= non-cooperative fallback wrappers =================
__global__ __launch_bounds__(256) void w_convhist(const int* __restrict__ A, int* __restrict__ bh,
                                                  int E, int HB, int NB,
                                                  const float* __restrict__ k,
                                                  unsigned int* __restrict__ kh, int total8) {
    __shared__ int h[256];
    int blk = blockIdx.x, t = threadIdx.x;
    if (blk >= HB) {
        int i = (blk - HB) * 256 + t;
        if (i < total8) dev_convert(k, kh, i);
        return;
    }
    dev_hist(A, bh, E, HB, NB, blk, t, h);
}
__global__ __launch_bounds__(256) void w_rowsum(const int* __restrict__ bh, int* __restrict__ rowsum, int HB) {
    __shared__ int scr[8];
    dev_rowsum(bh, rowsum, HB, blockIdx.x, threadIdx.x, scr);
}
__global__ __launch_bounds__(256) void w_scanbase(const int* __restrict__ rowsum, int* __restrict__ rowbase,
                                                  int* __restrict__ offsets, int NB, int N, int E) {
    __shared__ int scr[8];
    dev_scanbase(rowsum, rowbase, offsets, NB, N, E, threadIdx.x, scr);
}
__global__ __launch_bounds__(256) void w_rowscan(int* __restrict__ bh, const int* __restrict__ rowbase, int HB) {
    __shared__ int scr[8];
    dev_rowscan(bh, rowbase, HB, blockIdx.x, threadIdx.x, scr);
}
__global__ __launch_bounds__(256) void w_scatter(const int* __restrict__ A, const int* __restrict__ Bs,
                                                 const int* __restrict__ bh, int* __restrict__ tmp,
                                                 int E, int HB, int NB) {
    __shared__ int cur[256];
    dev_scatter(A, Bs, bh, tmp, E, HB, NB, blockIdx.x, threadIdx.x, cur);
}
__global__ __launch_bounds__(256) void w_build(const int* __restrict__ rowbase, const int* __restrict__ tmp,
                                               int* __restrict__ offsets, int* __restrict__ srcs,
                                               int N, int E, int NB) {
    __shared__ int cnt[256];
    __shared__ int scr[8];
    dev_build(rowbase, tmp, offsets, srcs, N, E, NB, blockIdx.x, threadIdx.x, cnt, scr);
}
__global__ __launch_bounds__(256) void w_node16(const float* __restrict__ q,
                                                const unsigned int* __restrict__ kh,
                                                const float* __restrict__ v,
                                                const int* __restrict__ offsets,
                                                const int* __restrict__ srcs,
                                                float* __restrict__ out, int N) {
    __shared__ float lds[4][1160];
    int t = threadIdx.x, lane = t & 63, wid = t >> 6;
    dev_node16(q, kh, v, offsets, srcs, out, N, blockIdx.x * 4 + wid, lane,
               &lds[wid][0], &lds[wid][8 * LPAD], &lds[wid][16 * LPAD]);
}
__global__ __launch_bounds__(256) void w_node32(const float* __restrict__ q, const float* __restrict__ k,
                                                const float* __restrict__ v,
                                                const int* __restrict__ offsets,
                                                const int* __restrict__ srcs,
                                                float* __restrict__ out, int N) {
    __shared__ float lds[4][1160];
    int t = threadIdx.x, lane = t & 63, wid = t >> 6;
    dev_node32(q, k, v, offsets, srcs, out, N, blockIdx.x * 4 + wid, lane,
               &lds[wid][0], &lds[wid][8 * LPAD], &lds[wid][16 * LPAD]);
}

// ================= host launcher =================
extern "C" void kernel_launch(void* const* d_in, const int* in_sizes, int n_in,
                              void* d_out, int out_size, void* d_ws, size_t ws_size,
                              hipStream_t stream) {
    const float* q  = (const float*)d_in[0];
    const float* k  = (const float*)d_in[1];
    const float* v  = (const float*)d_in[2];
    const int*   ei = (const int*)d_in[3];

    int N = in_sizes[0] / ROW;
    int E = in_sizes[3] / 2;
    const int* A  = ei;
    const int* Bs = ei + E;

    int HB = (E + EPB - 1) / EPB;       // edge chunks (391)
    int NB = (N + 255) >> 8;            // node buckets (196) -- requires N <= 65536

    // workspace layout (ints), then kh (f16 k) 256B-aligned
    int* offsets = (int*)d_ws;                       // N+1
    int* srcs    = offsets + (N + 1);                // E
    int* tmp     = srcs + E;                         // E
    int* bh      = tmp + E;                          // NB*HB
    int* rowsum  = bh + (size_t)NB * HB;             // NB
    int* rowbase = rowsum + NB;                      // NB+1
    size_t int_words = (size_t)(N + 1) + 2 * (size_t)E + (size_t)NB * HB + NB + (NB + 1);
    size_t kh_off = ((int_words * 4 + 255) & ~(size_t)255);
    unsigned int* kh = (unsigned int*)((char*)d_ws + kh_off);
    bool use_f16 = ws_size >= kh_off + (size_t)N * ROW * 2;
    int total8 = N * (ROW / 8);
    float* out = (float*)d_out;

    static int coop = -1, nCU = 0, maxB = 0;
    if (coop < 0) {
        int dev = 0;
        hipGetDevice(&dev);
        int ca = 0;
        hipDeviceGetAttribute(&ca, hipDeviceAttributeCooperativeLaunch, dev);
        hipDeviceGetAttribute(&nCU, hipDeviceAttributeMultiprocessorCount, dev);
        if (hipOccupancyMaxActiveBlocksPerMultiprocessor(&maxB, (const void*)mega_kernel, 256, 0)
            != hipSuccess) maxB = 0;
        coop = (ca != 0 && maxB > 0 && nCU > 0) ? 1 : 0;
    }

    bool launched = false;
    if (coop == 1) {
        int G = maxB * nCU;
        if (G > 4096) G = 4096;
        int usef16 = use_f16 ? 1 : 0;
        void* kp[] = {
            (void*)&q, (void*)&k, (void*)&v, (void*)&A, (void*)&Bs,
            (void*)&kh, (void*)&offsets, (void*)&srcs, (void*)&tmp, (void*)&bh,
            (void*)&rowsum, (void*)&rowbase, (void*)&out,
            (void*)&N, (void*)&E, (void*)&HB, (void*)&NB, (void*)&total8, (void*)&usef16
        };
        hipError_t err = hipLaunchCooperativeKernel((const void*)mega_kernel, dim3(G), dim3(256),
                                                    kp, 0, stream);
        if (err == hipSuccess) launched = true;
        else coop = 0;   // cooperative launch rejected (e.g. capture) -> fallback forever
    }

    if (!launched) {
        int CONVB = (total8 + 255) / 256;
        w_convhist<<<HB + (use_f16 ? CONVB : 0), 256, 0, stream>>>(A, bh, E, HB, NB, k, kh, total8);
        w_rowsum<<<NB, 256, 0, stream>>>(bh, rowsum, HB);
        w_scanbase<<<1, 256, 0, stream>>>(rowsum, rowbase, offsets, NB, N, E);
        w_rowscan<<<NB, 256, 0, stream>>>(bh, rowbase, HB);
        w_scatter<<<HB, 256, 0, stream>>>(A, Bs, bh, tmp, E, HB, NB);
        w_build<<<NB, 256, 0, stream>>>(rowbase, tmp, offsets, srcs, N, E, NB);
        if (use_f16)
            w_node16<<<(N + 3) / 4, 256, 0, stream>>>(q, kh, v, offsets, srcs, out, N);
        else
            w_node32<<<(N + 3) / 4, 256, 0, stream>>>(q, k, v, offsets, srcs, out, N);
    }
}

// Round 3
// 422.624 us; speedup vs baseline: 1.9345x; 1.9345x over previous
//
#include <hip/hip_runtime.h>
#include <hip/hip_fp16.h>

// Graph scaled-dot-product attention, N=50000, E=800000, H=8, D=64.
// seg_sum[n] = Q[n] @ (sum_{e:A_e=n} K[B_e])^T -- only Ksum needed per node.
// k pre-converted to f16 to halve gather bytes.
//
// Round-3 structure: 7 plain dispatches, NO cooperative launch (round 2: six
// grid.sync() burned ~700us spinning), NO single-block scan (round 1: ~250us
// serial on one CU), NO device-scope atomics (round 0: hist+scatter ~300us).
// Two-level LDS-atomic bucket sort with multi-block parallel matrix scan.
// All phase bodies are verified correct (rounds 1/2 passed, absmax 0.0156).

#define ROW 512          // H*D floats per node
#define LPAD 68          // padded LDS row stride (floats)
#define EPB 2048         // edges per hist/scatter chunk (256 thr * 8)

typedef float f4 __attribute__((ext_vector_type(4)));
typedef unsigned int u4 __attribute__((ext_vector_type(4)));

// ================= device phase functions =================

__device__ __forceinline__ void dev_convert(const float* __restrict__ k,
                                            unsigned int* __restrict__ kh, int i) {
    const f4* src = (const f4*)k + (size_t)i * 2;
    f4 x0 = __builtin_nontemporal_load(src);       // k f32 read once
    f4 x1 = __builtin_nontemporal_load(src + 1);
    union { __half2 h2; unsigned int u; } c0, c1, c2, c3;
    c0.h2 = __floats2half2_rn(x0.x, x0.y);
    c1.h2 = __floats2half2_rn(x0.z, x0.w);
    c2.h2 = __floats2half2_rn(x1.x, x1.y);
    c3.h2 = __floats2half2_rn(x1.z, x1.w);
    u4 o = {c0.u, c1.u, c2.u, c3.u};
    ((u4*)kh)[i] = o;
}

// block-wide exclusive scan over 256 ints (needs scr[4]+)
__device__ __forceinline__ int excl_scan_256(int x, int t, int* scr) {
    int lane = t & 63, w = t >> 6;
    int v = x;
    #pragma unroll
    for (int off = 1; off < 64; off <<= 1) {
        int u = __shfl_up(v, off, 64);
        if (lane >= off) v += u;
    }
    __syncthreads();
    if (lane == 63) scr[w] = v;
    __syncthreads();
    int base = 0;
    #pragma unroll
    for (int i = 0; i < 4; ++i) if (i < w) base += scr[i];
    return base + v - x;             // exclusive prefix
}

// ---------------- f16 accumulate helper ----------------
__device__ __forceinline__ void acc8(u4 x, f4& a0, f4& a1) {
    union { unsigned int u; __half2 h; } p0{x.x}, p1{x.y}, p2{x.z}, p3{x.w};
    a0.x += __low2float(p0.h); a0.y += __high2float(p0.h);
    a0.z += __low2float(p1.h); a0.w += __high2float(p1.h);
    a1.x += __low2float(p2.h); a1.y += __high2float(p2.h);
    a1.z += __low2float(p3.h); a1.w += __high2float(p3.h);
}

// ================= dispatch kernels =================

// ---- 1. convert k->f16 (blocks >= HB) + per-chunk bucket histogram (blocks < HB)
__global__ __launch_bounds__(256) void w_convhist(
    const int* __restrict__ A, int* __restrict__ bh, int E, int HB, int NB,
    const float* __restrict__ k, unsigned int* __restrict__ kh, int total8)
{
    __shared__ int h[256];
    int blk = blockIdx.x, t = threadIdx.x;
    if (blk >= HB) {                 // -------- convert part --------
        int i = (blk - HB) * 256 + t;
        if (i < total8) dev_convert(k, kh, i);
        return;
    }
    // -------- histogram part --------
    h[t] = 0;
    __syncthreads();
    int base = blk * EPB + t * 8;
    if (base + 8 <= E) {
        int4 a0 = *(const int4*)(A + base);
        int4 a1 = *(const int4*)(A + base + 4);
        atomicAdd(&h[a0.x >> 8], 1); atomicAdd(&h[a0.y >> 8], 1);
        atomicAdd(&h[a0.z >> 8], 1); atomicAdd(&h[a0.w >> 8], 1);
        atomicAdd(&h[a1.x >> 8], 1); atomicAdd(&h[a1.y >> 8], 1);
        atomicAdd(&h[a1.z >> 8], 1); atomicAdd(&h[a1.w >> 8], 1);
    } else {
        for (int j = 0; j < 8; ++j) { int i = base + j; if (i < E) atomicAdd(&h[A[i] >> 8], 1); }
    }
    __syncthreads();
    if (t < NB) bh[t * HB + blk] = h[t];   // bucket-major matrix
}

// ---- 2. per-bucket row sums (one block per bucket)
__global__ __launch_bounds__(256) void w_rowsum(const int* __restrict__ bh,
                                                int* __restrict__ rowsum, int HB) {
    __shared__ int scr[4];
    int g = blockIdx.x, t = threadIdx.x;
    int s = 0;
    for (int c = t; c < HB; c += 256) s += bh[g * HB + c];
    #pragma unroll
    for (int off = 32; off; off >>= 1) s += __shfl_down(s, off, 64);
    int lane = t & 63, w = t >> 6;
    if (lane == 0) scr[w] = s;
    __syncthreads();
    if (t == 0) rowsum[g] = scr[0] + scr[1] + scr[2] + scr[3];
}

// ---- 3. scan bucket bases (one tiny block over NB<=256 ints)
__global__ __launch_bounds__(256) void w_scanbase(const int* __restrict__ rowsum,
                                                  int* __restrict__ rowbase,
                                                  int* __restrict__ offsets,
                                                  int NB, int N, int E) {
    __shared__ int scr[4];
    int t = threadIdx.x;
    int x = (t < NB) ? rowsum[t] : 0;
    int p = excl_scan_256(x, t, scr);
    if (t <= NB) rowbase[t] = p;     // rowbase[NB] == E
    if (t == 0) offsets[N] = E;
}

// ---- 4. exclusive scan along each bucket row (one block per bucket)
__global__ __launch_bounds__(256) void w_rowscan(int* __restrict__ bh,
                                                 const int* __restrict__ rowbase, int HB) {
    __shared__ int scr[4];
    int g = blockIdx.x, t = threadIdx.x;
    int j0 = 2 * t, j1 = 2 * t + 1;
    int c0 = (j0 < HB) ? bh[g * HB + j0] : 0;
    int c1 = (j1 < HB) ? bh[g * HB + j1] : 0;
    int p = excl_scan_256(c0 + c1, t, scr);
    int base = rowbase[g];
    if (j0 < HB) bh[g * HB + j0] = base + p;
    if (j1 < HB) bh[g * HB + j1] = base + p + c0;
}

// ---- 5. scatter edges into bucket order (LDS cursors, no global atomics)
__global__ __launch_bounds__(256) void w_scatter(
    const int* __restrict__ A, const int* __restrict__ Bs, const int* __restrict__ bh,
    int* __restrict__ tmp, int E, int HB, int NB)
{
    __shared__ int cur[256];
    int blk = blockIdx.x, t = threadIdx.x;
    if (t < NB) cur[t] = bh[t * HB + blk];
    __syncthreads();
    int base = blk * EPB + t * 8;
    bool bal = ((((unsigned long long)(size_t)Bs) & 15) == 0);
    if (base + 8 <= E && bal) {
        int4 a0 = *(const int4*)(A + base);
        int4 a1 = *(const int4*)(A + base + 4);
        int4 b0 = *(const int4*)(Bs + base);
        int4 b1 = *(const int4*)(Bs + base + 4);
        int as[8] = {a0.x, a0.y, a0.z, a0.w, a1.x, a1.y, a1.z, a1.w};
        int bs[8] = {b0.x, b0.y, b0.z, b0.w, b1.x, b1.y, b1.z, b1.w};
        #pragma unroll
        for (int j = 0; j < 8; ++j) {
            int pos = atomicAdd(&cur[as[j] >> 8], 1);      // LDS atomic
            tmp[pos] = ((as[j] & 255) << 24) | bs[j];      // pack (A&255, B)
        }
    } else {
        for (int j = 0; j < 8; ++j) {
            int i = base + j;
            if (i < E) {
                int a = A[i], b = Bs[i];
                int pos = atomicAdd(&cur[a >> 8], 1);
                tmp[pos] = ((a & 255) << 24) | b;
            }
        }
    }
}

// ---- 6. per-bucket offsets + srcs (owner-computes, one block per bucket)
__global__ __launch_bounds__(256) void w_build(
    const int* __restrict__ rowbase, const int* __restrict__ tmp,
    int* __restrict__ offsets, int* __restrict__ srcs, int N, int E, int NB)
{
    __shared__ int cnt[256];
    __shared__ int scr[4];
    int g = blockIdx.x, t = threadIdx.x;
    int s = rowbase[g];
    int e = rowbase[g + 1];
    cnt[t] = 0;
    __syncthreads();
    for (int i = s + t; i < e; i += 256) atomicAdd(&cnt[(tmp[i] >> 24) & 255], 1);
    __syncthreads();
    int val = cnt[t];
    int p = excl_scan_256(val, t, scr);
    int n0 = (g << 8) + t;
    if (n0 < N) offsets[n0] = s + p;
    __syncthreads();
    cnt[t] = s + p;                  // reuse as cursor
    __syncthreads();
    for (int i = s + t; i < e; i += 256) {
        int wv = tmp[i];
        int pos = atomicAdd(&cnt[(wv >> 24) & 255], 1);   // LDS atomic
        srcs[pos] = wv & 0xFFFFFF;
    }
}

// ---- 7. node attention, f16 k (one wave per node)
__global__ __launch_bounds__(256) void w_node16(
    const float* __restrict__ q, const unsigned int* __restrict__ kh,
    const float* __restrict__ v, const int* __restrict__ offsets,
    const int* __restrict__ srcs, float* __restrict__ out, int N)
{
    __shared__ float lds[4][2 * 8 * LPAD + 64 + 8];
    int lane = threadIdx.x & 63;
    int wid  = threadIdx.x >> 6;
    int n = blockIdx.x * 4 + wid;
    bool active = n < N;

    float* qs = &lds[wid][0];
    float* ks = qs + 8 * LPAD;
    float* ps = ks + 8 * LPAD;

    int start = 0, end = 0;
    if (active) {
        start = __builtin_amdgcn_readfirstlane(offsets[n]);
        end   = __builtin_amdgcn_readfirstlane(offsets[n + 1]);
        int r0 = lane >> 4;
        int dq = (lane & 15) * 4;
        const f4* qn = (const f4*)(q + (size_t)n * ROW);
        f4 q0 = __builtin_nontemporal_load(qn + lane);
        f4 q1 = __builtin_nontemporal_load(qn + 64 + lane);
        *(f4*)(qs + r0 * LPAD + dq)       = q0;
        *(f4*)(qs + (r0 + 4) * LPAD + dq) = q1;
    }

    const u4* kh4 = (const u4*)kh;   // one u4 = 8 halves; one row = 64 u4
    f4 a0 = {0.f, 0.f, 0.f, 0.f}, a1 = {0.f, 0.f, 0.f, 0.f};
    int e = start;
    for (; e + 8 <= end; e += 8) {   // 8 independent 16B loads in flight
        int b0 = srcs[e],     b1 = srcs[e + 1], b2 = srcs[e + 2], b3 = srcs[e + 3];
        int b4 = srcs[e + 4], b5 = srcs[e + 5], b6 = srcs[e + 6], b7 = srcs[e + 7];
        u4 x0 = kh4[(size_t)b0 * 64 + lane];
        u4 x1 = kh4[(size_t)b1 * 64 + lane];
        u4 x2 = kh4[(size_t)b2 * 64 + lane];
        u4 x3 = kh4[(size_t)b3 * 64 + lane];
        u4 x4 = kh4[(size_t)b4 * 64 + lane];
        u4 x5 = kh4[(size_t)b5 * 64 + lane];
        u4 x6 = kh4[(size_t)b6 * 64 + lane];
        u4 x7 = kh4[(size_t)b7 * 64 + lane];
        acc8(x0, a0, a1); acc8(x1, a0, a1); acc8(x2, a0, a1); acc8(x3, a0, a1);
        acc8(x4, a0, a1); acc8(x5, a0, a1); acc8(x6, a0, a1); acc8(x7, a0, a1);
    }
    for (; e + 4 <= end; e += 4) {
        int b0 = srcs[e], b1 = srcs[e + 1], b2 = srcs[e + 2], b3 = srcs[e + 3];
        u4 x0 = kh4[(size_t)b0 * 64 + lane];
        u4 x1 = kh4[(size_t)b1 * 64 + lane];
        u4 x2 = kh4[(size_t)b2 * 64 + lane];
        u4 x3 = kh4[(size_t)b3 * 64 + lane];
        acc8(x0, a0, a1); acc8(x1, a0, a1); acc8(x2, a0, a1); acc8(x3, a0, a1);
    }
    for (; e < end; ++e) {
        u4 x = kh4[(size_t)srcs[e] * 64 + lane];
        acc8(x, a0, a1);
    }

    if (active) {
        // lane holds Ksum flat elems [lane*8, lane*8+8): row g = lane>>3, d=(lane&7)*8+j
        int g = lane >> 3;
        int dbase = (lane & 7) * 8;
        *(f4*)(ks + g * LPAD + dbase)     = a0;
        *(f4*)(ks + g * LPAD + dbase + 4) = a1;
    }
    __syncthreads();

    if (active) {
        int h = lane >> 3, g = lane & 7;
        const f4* qrow = (const f4*)(qs + h * LPAD);
        const f4* krow = (const f4*)(ks + g * LPAD);
        float acc = 0.f;
        #pragma unroll
        for (int i = 0; i < 16; ++i) {
            f4 qa = qrow[i];
            f4 kb = krow[i];
            acc += qa.x * kb.x + qa.y * kb.y + qa.z * kb.z + qa.w * kb.w;
        }
        int cnt = end - start;
        float score = acc / (float)((cnt > 0) ? cnt : 1);
        float mx = score;
        #pragma unroll
        for (int off = 1; off < 8; off <<= 1)
            mx = fmaxf(mx, __shfl_xor(mx, off, 8));
        float ex = __expf(score - mx);
        float sm = ex;
        #pragma unroll
        for (int off = 1; off < 8; off <<= 1)
            sm += __shfl_xor(sm, off, 8);
        ps[h * 8 + g] = ex / sm;
    }
    __syncthreads();

    if (active) {
        int h0 = lane >> 4;
        int dbase = (lane & 15) * 4;
        const float* vb = v + (size_t)n * ROW;
        f4 o0 = {0.f, 0.f, 0.f, 0.f}, o1 = {0.f, 0.f, 0.f, 0.f};
        #pragma unroll
        for (int g = 0; g < 8; ++g) {
            f4 vg = __builtin_nontemporal_load((const f4*)(vb + g * 64 + dbase));
            float p0 = ps[h0 * 8 + g];
            float p1 = ps[(h0 + 4) * 8 + g];
            o0 += p0 * vg;
            o1 += p1 * vg;
        }
        f4* ob = (f4*)(out + (size_t)n * ROW);
        __builtin_nontemporal_store(o0, ob + lane);
        __builtin_nontemporal_store(o1, ob + 64 + lane);
    }
}

// ---- 7'. node attention, f32 k (fallback if workspace too small)
__global__ __launch_bounds__(256) void w_node32(
    const float* __restrict__ q, const float* __restrict__ k,
    const float* __restrict__ v, const int* __restrict__ offsets,
    const int* __restrict__ srcs, float* __restrict__ out, int N)
{
    __shared__ float lds[4][2 * 8 * LPAD + 64 + 8];
    int lane = threadIdx.x & 63;
    int wid  = threadIdx.x >> 6;
    int n = blockIdx.x * 4 + wid;
    bool active = n < N;

    float* qs = &lds[wid][0];
    float* ks = qs + 8 * LPAD;
    float* ps = ks + 8 * LPAD;

    int start = 0, end = 0;
    if (active) { start = offsets[n]; end = offsets[n + 1]; }

    f4 a0 = {0.f, 0.f, 0.f, 0.f}, a1 = {0.f, 0.f, 0.f, 0.f};
    for (int e = start; e < end; ++e) {
        int b = srcs[e];
        const f4* kb = (const f4*)(k + (size_t)b * ROW);
        f4 x0 = kb[lane];
        f4 x1 = kb[64 + lane];
        a0 += x0; a1 += x1;
    }

    if (active) {
        int r0 = lane >> 4;
        int dbase = (lane & 15) * 4;
        *(f4*)(ks + r0 * LPAD + dbase)       = a0;
        *(f4*)(ks + (r0 + 4) * LPAD + dbase) = a1;
        const f4* qn = (const f4*)(q + (size_t)n * ROW);
        f4 q0 = qn[lane], q1 = qn[64 + lane];
        *(f4*)(qs + r0 * LPAD + dbase)       = q0;
        *(f4*)(qs + (r0 + 4) * LPAD + dbase) = q1;
    }
    __syncthreads();

    if (active) {
        int h = lane >> 3, g = lane & 7;
        const f4* qrow = (const f4*)(qs + h * LPAD);
        const f4* krow = (const f4*)(ks + g * LPAD);
        float acc = 0.f;
        #pragma unroll
        for (int i = 0; i < 16; ++i) {
            f4 qa = qrow[i];
            f4 kb = krow[i];
            acc += qa.x * kb.x + qa.y * kb.y + qa.z * kb.z + qa.w * kb.w;
        }
        int cnt = end - start;
        float score = acc / (float)((cnt > 0) ? cnt : 1);
        float mx = score;
        #pragma unroll
        for (int off = 1; off < 8; off <<= 1)
            mx = fmaxf(mx, __shfl_xor(mx, off, 8));
        float ex = __expf(score - mx);
        float sm = ex;
        #pragma unroll
        for (int off = 1; off < 8; off <<= 1)
            sm += __shfl_xor(sm, off, 8);
        ps[h * 8 + g] = ex / sm;
    }
    __syncthreads();

    if (active) {
        int h0 = lane >> 4;
        int dbase = (lane & 15) * 4;
        const float* vb = v + (size_t)n * ROW;
        f4 o0 = {0.f, 0.f, 0.f, 0.f}, o1 = {0.f, 0.f, 0.f, 0.f};
        #pragma unroll
        for (int g = 0; g < 8; ++g) {
            f4 vg = *(const f4*)(vb + g * 64 + dbase);
            float p0 = ps[h0 * 8 + g];
            float p1 = ps[(h0 + 4) * 8 + g];
            o0 += p0 * vg;
            o1 += p1 * vg;
        }
        f4* ob = (f4*)(out + (size_t)n * ROW);
        ob[lane]      = o0;
        ob[64 + lane] = o1;
    }
}

// ================= host launcher =================
extern "C" void kernel_launch(void* const* d_in, const int* in_sizes, int n_in,
                              void* d_out, int out_size, void* d_ws, size_t ws_size,
                              hipStream_t stream) {
    const float* q  = (const float*)d_in[0];
    const float* k  = (const float*)d_in[1];
    const float* v  = (const float*)d_in[2];
    const int*   ei = (const int*)d_in[3];

    int N = in_sizes[0] / ROW;
    int E = in_sizes[3] / 2;
    const int* A  = ei;
    const int* Bs = ei + E;

    int HB = (E + EPB - 1) / EPB;       // edge chunks (391)
    int NB = (N + 255) >> 8;            // node buckets (196) -- requires N <= 65536

    // workspace layout (ints), then kh (f16 k) 256B-aligned
    int* offsets = (int*)d_ws;                       // N+1
    int* srcs    = offsets + (N + 1);                // E
    int* tmp     = srcs + E;                         // E
    int* bh      = tmp + E;                          // NB*HB
    int* rowsum  = bh + (size_t)NB * HB;             // NB
    int* rowbase = rowsum + NB;                      // NB+1
    size_t int_words = (size_t)(N + 1) + 2 * (size_t)E + (size_t)NB * HB + NB + (NB + 1);
    size_t kh_off = ((int_words * 4 + 255) & ~(size_t)255);
    unsigned int* kh = (unsigned int*)((char*)d_ws + kh_off);
    bool use_f16 = ws_size >= kh_off + (size_t)N * ROW * 2;
    int total8 = N * (ROW / 8);
    int CONVB  = (total8 + 255) / 256;
    float* out = (float*)d_out;

    w_convhist<<<HB + (use_f16 ? CONVB : 0), 256, 0, stream>>>(A, bh, E, HB, NB, k, kh, total8);
    w_rowsum<<<NB, 256, 0, stream>>>(bh, rowsum, HB);
    w_scanbase<<<1, 256, 0, stream>>>(rowsum, rowbase, offsets, NB, N, E);
    w_rowscan<<<NB, 256, 0, stream>>>(bh, rowbase, HB);
    w_scatter<<<HB, 256, 0, stream>>>(A, Bs, bh, tmp, E, HB, NB);
    w_build<<<NB, 256, 0, stream>>>(rowbase, tmp, offsets, srcs, N, E, NB);
    if (use_f16)
        w_node16<<<(N + 3) / 4, 256, 0, stream>>>(q, kh, v, offsets, srcs, out, N);
    else
        w_node32<<<(N + 3) / 4, 256, 0, stream>>>(q, k, v, offsets, srcs, out, N);
}